// Round 1
// baseline (448.484 us; speedup 1.0000x reference)
//
#include <hip/hip_runtime.h>

typedef unsigned short ushortT;
typedef unsigned int uintT;
typedef __attribute__((ext_vector_type(8))) short s8v;   // 8 x bf16 bits
typedef __attribute__((ext_vector_type(4))) float f4v;

#define MFMA16(a,b,c) __builtin_amdgcn_mfma_f32_16x16x32_bf16(a,b,c,0,0,0)
#define MTOT 16384
#define XT_STRIDE 264                     // shorts per m-row (256 data + 8 pad)
#define XT_BATCH (16384 * 264)            // shorts per batch
#define XB32_SH 8448                      // shorts per 32-row x tile (32*264)
#define XB32_B  16896                     // bytes per 32-row x tile

#define GLL(g, l, sz) __builtin_amdgcn_global_load_lds( \
    (const __attribute__((address_space(1))) void*)(g), \
    (__attribute__((address_space(3))) void*)(l), (sz), 0, 0)

// stage 32-row m-tile tt2 (16896 B) into lds buffer (tt2&1); uses xt, xtb, lds, t
#define STAGE32(tt2) do { \
    const char* gb_ = (const char*)(xt + xtb) + (size_t)(tt2) * XB32_B; \
    char* lb_ = (char*)lds + (((tt2) & 1) ? XB32_B : 0); \
    _Pragma("unroll") \
    for (int i_ = 0; i_ < 4; ++i_) GLL(gb_ + i_ * 4096 + t * 16, lb_ + i_ * 4096 + t * 16, 16); \
    if (t < 128) GLL(gb_ + 16384 + t * 4, lb_ + 16384 + t * 4, 4); \
} while (0)

__device__ __forceinline__ ushortT f2bf(float f) {
    uintT u = __float_as_uint(f);
    u += 0x7FFFu + ((u >> 16) & 1u);   // RNE truncation to bf16
    return (ushortT)(u >> 16);
}
__device__ __forceinline__ uintT pack2(float a, float b) {
    return (uintT)f2bf(a) | ((uintT)f2bf(b) << 16);
}
__device__ __forceinline__ float elu1(float p) {
    return p > 0.f ? p + 1.f : __expf(p);
}

// K0: cast Wq,Wk to bf16 (concat layout [qk][256][256]) and zero A/qsum/ksum.
__global__ void k_prep(const float* __restrict__ wq, const float* __restrict__ wk,
                       ushortT* __restrict__ wqk, float* __restrict__ accz)
{
    int i = blockIdx.x * 256 + threadIdx.x;     // 0..65535
    wqk[i]         = f2bf(wq[i]);
    wqk[65536 + i] = f2bf(wk[i]);
    if (i < 36864) accz[i] = 0.f;               // A (32768) + qsum (2048) + ksum (2048)
}

// K0b: transpose+cast x [b][c][m] fp32 -> xt [b][m][264] bf16 (64x64 tiles)
// tile stride 66 (not 68): 16*33 % 32 == 16 so the transposed b16 reads are
// 2-way (free) instead of 4-way bank-conflicted.
__global__ __launch_bounds__(256) void k_tx(const float* __restrict__ x,
                                            ushortT* __restrict__ xt)
{
    __shared__ ushortT tile[64 * 66];          // [c][m] pad 64->66
    const int t = threadIdx.x;
    const int m0 = blockIdx.x * 64;
    const int ct = blockIdx.y & 3, b = blockIdx.y >> 2;
    const int c0 = ct * 64;

    const int cl = t >> 4, ml = (t & 15) * 4;
    #pragma unroll
    for (int i = 0; i < 4; ++i) {
        f4v v = *(const f4v*)(x + ((size_t)(b * 256 + c0 + cl + i * 16)) * MTOT + m0 + ml);
        uintT* w = (uintT*)&tile[(cl + i * 16) * 66 + ml];
        w[0] = pack2(v.x, v.y);
        w[1] = pack2(v.z, v.w);
    }
    __syncthreads();
    const int mr = t >> 2, cc = (t & 3) * 16;
    s8v o0, o1;
    #pragma unroll
    for (int u = 0; u < 8; ++u) o0[u] = (short)tile[(cc + u) * 66 + mr];
    #pragma unroll
    for (int u = 0; u < 8; ++u) o1[u] = (short)tile[(cc + 8 + u) * 66 + mr];
    ushortT* dst = xt + (size_t)b * XT_BATCH + (size_t)(m0 + mr) * XT_STRIDE + c0 + cc;
    *(s8v*)dst = o0;
    *(s8v*)(dst + 8) = o1;
}

// K1: q,k projection + elu + A/qsum/ksum. grid (64, 8): 8 m-tiles of 32 per block.
// 32-row tiles cut LDS to 44032 B -> 3 blocks/CU (was 2). qsum/ksum computed on
// the matrix pipe via an all-ones B fragment (replaces per-tile shfl butterflies).
__global__ __launch_bounds__(256, 2) void k_qk(
    const ushortT* __restrict__ xt, const ushortT* __restrict__ wqk,
    float* __restrict__ Ag, float* __restrict__ qsg, float* __restrict__ ksg)
{
    __shared__ __align__(16) ushortT lds[2 * XB32_SH + 4 * 1280]; // 44032 B
    const int t = threadIdx.x;
    const int wv = t >> 6, lane = t & 63, quad = lane >> 4, l15 = lane & 15;
    const int b = blockIdx.y;
    const size_t xtb = (size_t)b * XT_BATCH + (size_t)(blockIdx.x * 256) * XT_STRIDE;

    ushortT* gram = lds + 2 * XB32_SH + wv * 1280;   // 32 rows x 40 shorts, per-wave
    float* gramf = (float*)gram;

    f4v accA[4], sQ[4], sK[4];
    #pragma unroll
    for (int i = 0; i < 4; ++i) {
        accA[i] = (f4v){0,0,0,0};
        sQ[i]   = (f4v){0,0,0,0};
        sK[i]   = (f4v){0,0,0,0};
    }
    s8v ones;
    #pragma unroll
    for (int u = 0; u < 8; ++u) ones[u] = (short)0x3F80;   // bf16 1.0

    const ushortT* wq_base = wqk + (wv * 64 + l15) * 256 + quad * 8;
    const ushortT* wk_base = wq_base + 65536;

    STAGE32(0);

    for (int tt = 0; tt < 8; ++tt) {
        __syncthreads();                           // buf[tt&1] ready
        if (tt < 7) STAGE32(tt + 1);               // prefetch next tile -> other buf
        const ushortT* xb = lds + (tt & 1) * XB32_SH;

        f4v aq[4][2], ak[4][2];
        #pragma unroll
        for (int i = 0; i < 4; ++i)
            #pragma unroll
            for (int j = 0; j < 2; ++j) { aq[i][j] = (f4v){0,0,0,0}; ak[i][j] = (f4v){0,0,0,0}; }

        #pragma unroll 2
        for (int kc = 0; kc < 8; ++kc) {
            s8v afq[4], afk[4], bf[2];
            #pragma unroll
            for (int ot = 0; ot < 4; ++ot)
                afq[ot] = *(const s8v*)(wq_base + ot * 16 * 256 + kc * 32);
            #pragma unroll
            for (int ot = 0; ot < 4; ++ot)
                afk[ot] = *(const s8v*)(wk_base + ot * 16 * 256 + kc * 32);
            #pragma unroll
            for (int j = 0; j < 2; ++j)
                bf[j] = *(const s8v*)&xb[(j * 16 + l15) * XT_STRIDE + kc * 32 + quad * 8];
            #pragma unroll
            for (int ot = 0; ot < 4; ++ot)
                #pragma unroll
                for (int j = 0; j < 2; ++j)
                    aq[ot][j] = MFMA16(afq[ot], bf[j], aq[ot][j]);
            #pragma unroll
            for (int ot = 0; ot < 4; ++ot)
                #pragma unroll
                for (int j = 0; j < 2; ++j)
                    ak[ot][j] = MFMA16(afk[ot], bf[j], ak[ot][j]);
        }

        // elu in place (C layout: row = ot*16+quad*4+r, m = j*16+l15)
        #pragma unroll
        for (int ot = 0; ot < 4; ++ot)
            #pragma unroll
            for (int j = 0; j < 2; ++j)
                #pragma unroll
                for (int r = 0; r < 4; ++r) {
                    aq[ot][j][r] = elu1(aq[ot][j][r]);
                    ak[ot][j][r] = elu1(ak[ot][j][r]);
                }

        // Gram + row sums per ot: q rows 0..15, k rows 16..31 of the per-wave region.
        // sums via MFMA with all-ones B: D[d][*] = sum_m q[d,m] (every column equal).
        #pragma unroll
        for (int ot = 0; ot < 4; ++ot) {
            #pragma unroll
            for (int jj = 0; jj < 2; ++jj)
                #pragma unroll
                for (int r = 0; r < 4; ++r) {
                    int d = quad * 4 + r;
                    gram[d * 40 + jj * 16 + l15]        = f2bf(aq[ot][jj][r]);
                    gram[(16 + d) * 40 + jj * 16 + l15] = f2bf(ak[ot][jj][r]);
                }
            s8v qa = *(const s8v*)&gram[l15 * 40 + quad * 8];
            s8v kb = *(const s8v*)&gram[(16 + l15) * 40 + quad * 8];
            accA[ot] = MFMA16(qa, kb, accA[ot]);
            sQ[ot]   = MFMA16(qa, ones, sQ[ot]);
            sK[ot]   = MFMA16(kb, ones, sK[ot]);
        }
    }

    // final: Ag atomics (full 64B lines)
    #pragma unroll
    for (int ot = 0; ot < 4; ++ot)
        #pragma unroll
        for (int r = 0; r < 4; ++r)
            atomicAdd(Ag + ((b * 16 + wv * 4 + ot) * 16 + quad * 4 + r) * 16 + l15, accA[ot][r]);

    // final: qsum/ksum via gram region -> one coalesced 64-lane atomic each.
    // sQ[ot][r] holds sum for row ot*16+quad*4+r (replicated across l15).
    if (l15 == 0) {
        #pragma unroll
        for (int ot = 0; ot < 4; ++ot)
            #pragma unroll
            for (int r = 0; r < 4; ++r) {
                int row = ot * 16 + quad * 4 + r;
                gramf[row]      = sQ[ot][r];
                gramf[64 + row] = sK[ot][r];
            }
    }
    float myq = gramf[lane];
    float myk = gramf[64 + lane];
    atomicAdd(qsg + b * 256 + wv * 64 + lane, myq);
    atomicAdd(ksg + b * 256 + wv * 64 + lane, myk);
}

// K2: Weff[b, h*16+d, c] = z[b,d] * sum_e A[b,h,d,e] * wv[h*16+e, c]  (z of HEAD d)
__global__ __launch_bounds__(256) void k_weff(
    const float* __restrict__ wvw, const float* __restrict__ Ag,
    const float* __restrict__ qsg, const float* __restrict__ ksg,
    ushortT* __restrict__ weff)
{
    __shared__ float A_l[256];
    __shared__ float z_l[16];
    const int t = threadIdx.x;
    const int h = blockIdx.x, b = blockIdx.y;
    A_l[t] = Ag[(b * 16 + h) * 256 + t];
    if (t < 16) {
        float s = 0.f;
        #pragma unroll
        for (int d = 0; d < 16; ++d)
            s += qsg[b * 256 + t * 16 + d] * ksg[b * 256 + t * 16 + d];
        z_l[t] = 1.f / (s + 1e-6f);
    }
    __syncthreads();
    float acc[16];
    #pragma unroll
    for (int d = 0; d < 16; ++d) acc[d] = 0.f;
    #pragma unroll 4
    for (int e = 0; e < 16; ++e) {
        float w = wvw[(h * 16 + e) * 256 + t];
        #pragma unroll
        for (int d = 0; d < 16; ++d) acc[d] += A_l[d * 16 + e] * w;
    }
    #pragma unroll
    for (int d = 0; d < 16; ++d)
        weff[((size_t)b * 256 + h * 16 + d) * 256 + t] = f2bf(acc[d] * z_l[d]);
}

// K3: out[b] = Weff[b] @ x[b]. grid (64, 8): 8 m-tiles of 32 per block,
// double-buffered; LDS 33792 B -> 4 blocks/CU by LDS.
__global__ __launch_bounds__(256, 2) void k_out(
    const ushortT* __restrict__ xt, const ushortT* __restrict__ weff,
    float* __restrict__ out)
{
    __shared__ __align__(16) ushortT lds[2 * XB32_SH];   // 33792 B
    const int t = threadIdx.x;
    const int wv = t >> 6, lane = t & 63, quad = lane >> 4, l15 = lane & 15;
    const int b = blockIdx.y;
    const size_t xtb = (size_t)b * XT_BATCH + (size_t)(blockIdx.x * 256) * XT_STRIDE;

    const ushortT* w_base = weff + (size_t)b * 65536 + (wv * 64 + l15) * 256 + quad * 8;

    STAGE32(0);

    for (int tt = 0; tt < 8; ++tt) {
        __syncthreads();
        if (tt < 7) STAGE32(tt + 1);
        const ushortT* xb = lds + (tt & 1) * XB32_SH;

        f4v acc[4][2];
        #pragma unroll
        for (int i = 0; i < 4; ++i)
            #pragma unroll
            for (int j = 0; j < 2; ++j) acc[i][j] = (f4v){0,0,0,0};

        #pragma unroll 2
        for (int kc = 0; kc < 8; ++kc) {
            s8v af[4], bf[2];
            #pragma unroll
            for (int ot = 0; ot < 4; ++ot)
                af[ot] = *(const s8v*)(w_base + ot * 16 * 256 + kc * 32);
            #pragma unroll
            for (int j = 0; j < 2; ++j)
                bf[j] = *(const s8v*)&xb[(j * 16 + l15) * XT_STRIDE + kc * 32 + quad * 8];
            #pragma unroll
            for (int ot = 0; ot < 4; ++ot)
                #pragma unroll
                for (int j = 0; j < 2; ++j)
                    acc[ot][j] = MFMA16(af[ot], bf[j], acc[ot][j]);
        }

        const int m0 = blockIdx.x * 256 + tt * 32;
        #pragma unroll
        for (int ot = 0; ot < 4; ++ot)
            #pragma unroll
            for (int j = 0; j < 2; ++j)
                #pragma unroll
                for (int r = 0; r < 4; ++r)
                    out[((size_t)b * 256 + wv * 64 + ot * 16 + quad * 4 + r) * MTOT
                        + m0 + j * 16 + l15] = acc[ot][j][r];
    }
}

extern "C" void kernel_launch(void* const* d_in, const int* in_sizes, int n_in,
                              void* d_out, int out_size, void* d_ws, size_t ws_size,
                              hipStream_t stream)
{
    const float* x   = (const float*)d_in[0];
    const float* wq  = (const float*)d_in[1];
    const float* wk  = (const float*)d_in[2];
    const float* wvw = (const float*)d_in[3];
    float* out = (float*)d_out;
    char* ws = (char*)d_ws;
    // ws layout: wqk bf16 262144 | Ag 131072 | qsg 8192 | ksg 8192 | weff 1048576 | xt 69206016
    ushortT* wqk  = (ushortT*)ws;
    float*   Ag   = (float*)(ws + 262144);
    float*   qsg  = (float*)(ws + 393216);
    float*   ksg  = (float*)(ws + 401408);
    ushortT* weff = (ushortT*)(ws + 409600);
    ushortT* xt   = (ushortT*)(ws + 1458176);

    hipLaunchKernelGGL(k_prep, dim3(256), dim3(256), 0, stream, wq, wk, wqk, Ag);
    hipLaunchKernelGGL(k_tx,   dim3(256, 32), dim3(256), 0, stream, x, xt);
    hipLaunchKernelGGL(k_qk,   dim3(64, 8), dim3(256), 0, stream, xt, wqk, Ag, qsg, ksg);
    hipLaunchKernelGGL(k_weff, dim3(16, 8),  dim3(256), 0, stream, wvw, Ag, qsg, ksg, weff);
    hipLaunchKernelGGL(k_out,  dim3(64, 8), dim3(256), 0, stream, xt, weff, out);
}

// Round 2
// 398.886 us; speedup vs baseline: 1.1243x; 1.1243x over previous
//
#include <hip/hip_runtime.h>

typedef unsigned short ushortT;
typedef unsigned int uintT;
typedef __attribute__((ext_vector_type(8))) short s8v;   // 8 x bf16 bits
typedef __attribute__((ext_vector_type(4))) float f4v;

#define MFMA16(a,b,c) __builtin_amdgcn_mfma_f32_16x16x32_bf16(a,b,c,0,0,0)
#define MTOT 16384
#define XT_STRIDE 264                     // shorts per m-row (256 data + 8 pad)
#define XT_BATCH (16384 * 264)            // shorts per batch
#define XB64_SH 16896                     // shorts per 64-row x tile
#define XB64_B  33792                     // bytes per 64-row x tile

#define GLL(g, l, sz) __builtin_amdgcn_global_load_lds( \
    (const __attribute__((address_space(1))) void*)(g), \
    (__attribute__((address_space(3))) void*)(l), (sz), 0, 0)

// stage one 64-row m-tile (33792 B) into lds[0..]; uses xt, xtb, lds, t
#define STAGE64() do { \
    const char* gb_ = (const char*)(xt + xtb); \
    char* lb_ = (char*)lds; \
    _Pragma("unroll") \
    for (int i_ = 0; i_ < 8; ++i_) GLL(gb_ + i_ * 4096 + t * 16, lb_ + i_ * 4096 + t * 16, 16); \
    GLL(gb_ + 32768 + t * 4, lb_ + 32768 + t * 4, 4); \
} while (0)

__device__ __forceinline__ ushortT f2bf(float f) {
    uintT u = __float_as_uint(f);
    u += 0x7FFFu + ((u >> 16) & 1u);   // RNE truncation to bf16
    return (ushortT)(u >> 16);
}
__device__ __forceinline__ uintT pack2(float a, float b) {
    return (uintT)f2bf(a) | ((uintT)f2bf(b) << 16);
}
__device__ __forceinline__ float elu1(float p) {
    return p > 0.f ? p + 1.f : __expf(p);
}

// K0: cast Wq,Wk to bf16 (concat layout [qk][256][256]) and zero A/qsum/ksum.
__global__ void k_prep(const float* __restrict__ wq, const float* __restrict__ wk,
                       ushortT* __restrict__ wqk, float* __restrict__ accz)
{
    int i = blockIdx.x * 256 + threadIdx.x;     // 0..65535
    wqk[i]         = f2bf(wq[i]);
    wqk[65536 + i] = f2bf(wk[i]);
    if (i < 36864) accz[i] = 0.f;               // A (32768) + qsum (2048) + ksum (2048)
}

// K0b: transpose+cast x [b][c][m] fp32 -> xt [b][m][264] bf16 (64x64 tiles)
// tile stride 66: 16*33 % 32 == 16 so transposed b16 reads are 2-way (free).
__global__ __launch_bounds__(256) void k_tx(const float* __restrict__ x,
                                            ushortT* __restrict__ xt)
{
    __shared__ ushortT tile[64 * 66];          // [c][m] pad 64->66
    const int t = threadIdx.x;
    const int m0 = blockIdx.x * 64;
    const int ct = blockIdx.y & 3, b = blockIdx.y >> 2;
    const int c0 = ct * 64;

    const int cl = t >> 4, ml = (t & 15) * 4;
    #pragma unroll
    for (int i = 0; i < 4; ++i) {
        f4v v = *(const f4v*)(x + ((size_t)(b * 256 + c0 + cl + i * 16)) * MTOT + m0 + ml);
        uintT* w = (uintT*)&tile[(cl + i * 16) * 66 + ml];
        w[0] = pack2(v.x, v.y);
        w[1] = pack2(v.z, v.w);
    }
    __syncthreads();
    const int mr = t >> 2, cc = (t & 3) * 16;
    s8v o0, o1;
    #pragma unroll
    for (int u = 0; u < 8; ++u) o0[u] = (short)tile[(cc + u) * 66 + mr];
    #pragma unroll
    for (int u = 0; u < 8; ++u) o1[u] = (short)tile[(cc + 8 + u) * 66 + mr];
    ushortT* dst = xt + (size_t)b * XT_BATCH + (size_t)(m0 + mr) * XT_STRIDE + c0 + cc;
    *(s8v*)dst = o0;
    *(s8v*)(dst + 8) = o1;
}

// K1: q,k projection + elu + A/qsum/ksum.
// grid (256, 8): ONE 64-row m-tile per block -> 2048 blocks, 3 blocks/CU
// (LDS 44032 B, ~155 VGPR via ot-pair split). One barrier per block.
// qsum/ksum on the matrix pipe via all-ones B fragment.
__global__ __launch_bounds__(256, 3) void k_qk(
    const ushortT* __restrict__ xt, const ushortT* __restrict__ wqk,
    float* __restrict__ Ag, float* __restrict__ qsg, float* __restrict__ ksg)
{
    __shared__ __align__(16) ushortT lds[XB64_SH + 4 * 1280];   // 44032 B
    const int t = threadIdx.x;
    const int wv = t >> 6, lane = t & 63, quad = lane >> 4, l15 = lane & 15;
    const int b = blockIdx.y;
    const size_t xtb = (size_t)b * XT_BATCH + (size_t)(blockIdx.x * 64) * XT_STRIDE;

    ushortT* gram = lds + XB64_SH + wv * 1280;   // 32 rows x 40 shorts, per-wave
    float* gramf = (float*)gram;

    f4v accA[4], sQ[4], sK[4];
    #pragma unroll
    for (int i = 0; i < 4; ++i) {
        accA[i] = (f4v){0,0,0,0};
        sQ[i]   = (f4v){0,0,0,0};
        sK[i]   = (f4v){0,0,0,0};
    }
    s8v ones;
    #pragma unroll
    for (int u = 0; u < 8; ++u) ones[u] = (short)0x3F80;   // bf16 1.0

    const ushortT* wq_base = wqk + (wv * 64 + l15) * 256 + quad * 8;

    STAGE64();
    __syncthreads();                              // waits vmcnt(0): tile resident
    const ushortT* xb = lds;

    #pragma unroll
    for (int op = 0; op < 2; ++op) {              // ot-pair split: caps live regs
        f4v aq[2][4], ak[2][4];
        #pragma unroll
        for (int oo = 0; oo < 2; ++oo)
            #pragma unroll
            for (int j = 0; j < 4; ++j) { aq[oo][j] = (f4v){0,0,0,0}; ak[oo][j] = (f4v){0,0,0,0}; }

        #pragma unroll 2
        for (int kc = 0; kc < 8; ++kc) {
            s8v afq[2], afk[2], bfv[4];
            #pragma unroll
            for (int oo = 0; oo < 2; ++oo) {
                const ushortT* wb = wq_base + (op * 2 + oo) * 16 * 256 + kc * 32;
                afq[oo] = *(const s8v*)wb;
                afk[oo] = *(const s8v*)(wb + 65536);
            }
            #pragma unroll
            for (int j = 0; j < 4; ++j)
                bfv[j] = *(const s8v*)&xb[(j * 16 + l15) * XT_STRIDE + kc * 32 + quad * 8];
            #pragma unroll
            for (int oo = 0; oo < 2; ++oo)
                #pragma unroll
                for (int j = 0; j < 4; ++j)
                    aq[oo][j] = MFMA16(afq[oo], bfv[j], aq[oo][j]);
            #pragma unroll
            for (int oo = 0; oo < 2; ++oo)
                #pragma unroll
                for (int j = 0; j < 4; ++j)
                    ak[oo][j] = MFMA16(afk[oo], bfv[j], ak[oo][j]);
        }

        // elu in place (C layout: row = (op*2+oo)*16+quad*4+r, m = j*16+l15)
        #pragma unroll
        for (int oo = 0; oo < 2; ++oo)
            #pragma unroll
            for (int j = 0; j < 4; ++j)
                #pragma unroll
                for (int r = 0; r < 4; ++r) {
                    aq[oo][j][r] = elu1(aq[oo][j][r]);
                    ak[oo][j][r] = elu1(ak[oo][j][r]);
                }

        // Gram + row sums: q rows 0..15, k rows 16..31 of per-wave region.
        #pragma unroll
        for (int oo = 0; oo < 2; ++oo) {
            const int ot = op * 2 + oo;
            #pragma unroll
            for (int hf = 0; hf < 2; ++hf) {
                #pragma unroll
                for (int jj = 0; jj < 2; ++jj)
                    #pragma unroll
                    for (int r = 0; r < 4; ++r) {
                        int d = quad * 4 + r;
                        gram[d * 40 + jj * 16 + l15]        = f2bf(aq[oo][hf * 2 + jj][r]);
                        gram[(16 + d) * 40 + jj * 16 + l15] = f2bf(ak[oo][hf * 2 + jj][r]);
                    }
                s8v qa = *(const s8v*)&gram[l15 * 40 + quad * 8];
                s8v kb = *(const s8v*)&gram[(16 + l15) * 40 + quad * 8];
                accA[ot] = MFMA16(qa, kb, accA[ot]);
                sQ[ot]   = MFMA16(qa, ones, sQ[ot]);
                sK[ot]   = MFMA16(kb, ones, sK[ot]);
            }
        }
    }

    // final: Ag atomics (full 64B lines)
    #pragma unroll
    for (int ot = 0; ot < 4; ++ot)
        #pragma unroll
        for (int r = 0; r < 4; ++r)
            atomicAdd(Ag + ((b * 16 + wv * 4 + ot) * 16 + quad * 4 + r) * 16 + l15, accA[ot][r]);

    // final: qsum/ksum via gram region -> one coalesced 64-lane atomic each.
    if (l15 == 0) {
        #pragma unroll
        for (int ot = 0; ot < 4; ++ot)
            #pragma unroll
            for (int r = 0; r < 4; ++r) {
                int row = ot * 16 + quad * 4 + r;
                gramf[row]      = sQ[ot][r];
                gramf[64 + row] = sK[ot][r];
            }
    }
    float myq = gramf[lane];
    float myk = gramf[64 + lane];
    atomicAdd(qsg + b * 256 + wv * 64 + lane, myq);
    atomicAdd(ksg + b * 256 + wv * 64 + lane, myk);
}

// K2: Weff[b, h*16+d, c] = z[b,d] * sum_e A[b,h,d,e] * wv[h*16+e, c]  (z of HEAD d)
__global__ __launch_bounds__(256) void k_weff(
    const float* __restrict__ wvw, const float* __restrict__ Ag,
    const float* __restrict__ qsg, const float* __restrict__ ksg,
    ushortT* __restrict__ weff)
{
    __shared__ float A_l[256];
    __shared__ float z_l[16];
    const int t = threadIdx.x;
    const int h = blockIdx.x, b = blockIdx.y;
    A_l[t] = Ag[(b * 16 + h) * 256 + t];
    if (t < 16) {
        float s = 0.f;
        #pragma unroll
        for (int d = 0; d < 16; ++d)
            s += qsg[b * 256 + t * 16 + d] * ksg[b * 256 + t * 16 + d];
        z_l[t] = 1.f / (s + 1e-6f);
    }
    __syncthreads();
    float acc[16];
    #pragma unroll
    for (int d = 0; d < 16; ++d) acc[d] = 0.f;
    #pragma unroll 4
    for (int e = 0; e < 16; ++e) {
        float w = wvw[(h * 16 + e) * 256 + t];
        #pragma unroll
        for (int d = 0; d < 16; ++d) acc[d] += A_l[d * 16 + e] * w;
    }
    #pragma unroll
    for (int d = 0; d < 16; ++d)
        weff[((size_t)b * 256 + h * 16 + d) * 256 + t] = f2bf(acc[d] * z_l[d]);
}

// K3: out[b] = Weff[b] @ x[b]. grid (256, 8): ONE 64-row m-tile per block.
// LDS 33792 B -> 4 blocks/CU; acc[4][4]+frags fit 128 VGPR.
__global__ __launch_bounds__(256, 4) void k_out(
    const ushortT* __restrict__ xt, const ushortT* __restrict__ weff,
    float* __restrict__ out)
{
    __shared__ __align__(16) ushortT lds[XB64_SH];   // 33792 B
    const int t = threadIdx.x;
    const int wv = t >> 6, lane = t & 63, quad = lane >> 4, l15 = lane & 15;
    const int b = blockIdx.y;
    const size_t xtb = (size_t)b * XT_BATCH + (size_t)(blockIdx.x * 64) * XT_STRIDE;

    const ushortT* w_base = weff + (size_t)b * 65536 + (wv * 64 + l15) * 256 + quad * 8;

    STAGE64();
    __syncthreads();
    const ushortT* xb = lds;

    f4v acc[4][4];
    #pragma unroll
    for (int i = 0; i < 4; ++i)
        #pragma unroll
        for (int j = 0; j < 4; ++j) acc[i][j] = (f4v){0,0,0,0};

    #pragma unroll 2
    for (int kc = 0; kc < 8; ++kc) {
        s8v af[4], bfv[4];
        #pragma unroll
        for (int ot = 0; ot < 4; ++ot)
            af[ot] = *(const s8v*)(w_base + ot * 16 * 256 + kc * 32);
        #pragma unroll
        for (int j = 0; j < 4; ++j)
            bfv[j] = *(const s8v*)&xb[(j * 16 + l15) * XT_STRIDE + kc * 32 + quad * 8];
        #pragma unroll
        for (int ot = 0; ot < 4; ++ot)
            #pragma unroll
            for (int j = 0; j < 4; ++j)
                acc[ot][j] = MFMA16(af[ot], bfv[j], acc[ot][j]);
    }

    const int m0 = blockIdx.x * 64;
    #pragma unroll
    for (int ot = 0; ot < 4; ++ot)
        #pragma unroll
        for (int j = 0; j < 4; ++j)
            #pragma unroll
            for (int r = 0; r < 4; ++r)
                out[((size_t)b * 256 + wv * 64 + ot * 16 + quad * 4 + r) * MTOT
                    + m0 + j * 16 + l15] = acc[ot][j][r];
}

extern "C" void kernel_launch(void* const* d_in, const int* in_sizes, int n_in,
                              void* d_out, int out_size, void* d_ws, size_t ws_size,
                              hipStream_t stream)
{
    const float* x   = (const float*)d_in[0];
    const float* wq  = (const float*)d_in[1];
    const float* wk  = (const float*)d_in[2];
    const float* wvw = (const float*)d_in[3];
    float* out = (float*)d_out;
    char* ws = (char*)d_ws;
    // ws layout: wqk bf16 262144 | Ag 131072 | qsg 8192 | ksg 8192 | weff 1048576 | xt 69206016
    ushortT* wqk  = (ushortT*)ws;
    float*   Ag   = (float*)(ws + 262144);
    float*   qsg  = (float*)(ws + 393216);
    float*   ksg  = (float*)(ws + 401408);
    ushortT* weff = (ushortT*)(ws + 409600);
    ushortT* xt   = (ushortT*)(ws + 1458176);

    hipLaunchKernelGGL(k_prep, dim3(256), dim3(256), 0, stream, wq, wk, wqk, Ag);
    hipLaunchKernelGGL(k_tx,   dim3(256, 32), dim3(256), 0, stream, x, xt);
    hipLaunchKernelGGL(k_qk,   dim3(256, 8), dim3(256), 0, stream, xt, wqk, Ag, qsg, ksg);
    hipLaunchKernelGGL(k_weff, dim3(16, 8),  dim3(256), 0, stream, wvw, Ag, qsg, ksg, weff);
    hipLaunchKernelGGL(k_out,  dim3(256, 8), dim3(256), 0, stream, xt, weff, out);
}

// Round 3
// 359.743 us; speedup vs baseline: 1.2467x; 1.1088x over previous
//
#include <hip/hip_runtime.h>

typedef unsigned short ushortT;
typedef unsigned int uintT;
typedef __attribute__((ext_vector_type(8))) short s8v;   // 8 x bf16 bits
typedef __attribute__((ext_vector_type(4))) float f4v;

#define MFMA16(a,b,c) __builtin_amdgcn_mfma_f32_16x16x32_bf16(a,b,c,0,0,0)
#define MTOT 16384
#define XT_STRIDE 264                     // shorts per m-row (256 data + 8 pad)
#define XT_BATCH (16384 * 264)            // shorts per batch
#define XB64_SH 16896                     // shorts per 64-row x tile
#define XB64_B  33792                     // bytes per 64-row x tile

#define GLL(g, l, sz) __builtin_amdgcn_global_load_lds( \
    (const __attribute__((address_space(1))) void*)(g), \
    (__attribute__((address_space(3))) void*)(l), (sz), 0, 0)

// stage one 64-row m-tile (33792 B) into lds[0..]; uses xt, xtb, lds, t
#define STAGE64() do { \
    const char* gb_ = (const char*)(xt + xtb); \
    char* lb_ = (char*)lds; \
    _Pragma("unroll") \
    for (int i_ = 0; i_ < 8; ++i_) GLL(gb_ + i_ * 4096 + t * 16, lb_ + i_ * 4096 + t * 16, 16); \
    GLL(gb_ + 32768 + t * 4, lb_ + 32768 + t * 4, 4); \
} while (0)

__device__ __forceinline__ ushortT f2bf(float f) {
    uintT u = __float_as_uint(f);
    u += 0x7FFFu + ((u >> 16) & 1u);   // RNE truncation to bf16
    return (ushortT)(u >> 16);
}
__device__ __forceinline__ uintT pack2(float a, float b) {
    return (uintT)f2bf(a) | ((uintT)f2bf(b) << 16);
}
__device__ __forceinline__ float elu1(float p) {
    return p > 0.f ? p + 1.f : __expf(p);
}

// K0: cast Wq,Wk to bf16 (concat layout [qk][256][256]) and zero A/qsum/ksum.
__global__ void k_prep(const float* __restrict__ wq, const float* __restrict__ wk,
                       ushortT* __restrict__ wqk, float* __restrict__ accz)
{
    int i = blockIdx.x * 256 + threadIdx.x;     // 0..65535
    wqk[i]         = f2bf(wq[i]);
    wqk[65536 + i] = f2bf(wk[i]);
    if (i < 36864) accz[i] = 0.f;               // A (32768) + qsum (2048) + ksum (2048)
}

// K1 (fused): transpose+cast x -> LDS xtile (and global xt for k_out), then
// q,k projection + elu + A/qsum/ksum from LDS. grid (256, 8): one 64-m tile
// per block. LDS 52480 B -> 3 blocks/CU. Replaces the old k_tx + k_qk pair:
// x is read ONCE from HBM, transposed in LDS (k_tx's proven 64x66 pattern),
// consumed by MFMA directly, and the bf16 tile is streamed out for k_out.
__global__ __launch_bounds__(256, 3) void k_qkt(
    const float* __restrict__ x, const ushortT* __restrict__ wqk,
    ushortT* __restrict__ xt, float* __restrict__ Ag,
    float* __restrict__ qsg, float* __restrict__ ksg)
{
    // layout: xtile [64][264] | tile1 [64][66] | gram 4 x 1280
    __shared__ __align__(16) ushortT lds[XB64_SH + 4224 + 4 * 1280];   // 52480 B
    const int t = threadIdx.x;
    const int wv = t >> 6, lane = t & 63, quad = lane >> 4, l15 = lane & 15;
    const int b = blockIdx.y;
    const int m0 = blockIdx.x * 64;
    const size_t xtb = (size_t)b * XT_BATCH + (size_t)m0 * XT_STRIDE;

    ushortT* xtile = lds;
    ushortT* tile1 = lds + XB64_SH;
    ushortT* gram  = lds + XB64_SH + 4224 + wv * 1280;   // 32 rows x 40 shorts
    float* gramf = (float*)gram;

    // ---- transpose phase: x [c][m] fp32 -> xtile [m][c] bf16, 4 c-chunks ----
    {
        const int cl = t >> 4, ml = (t & 15) * 4;
        const int mr = t >> 2, cc = (t & 3) * 16;
        #pragma unroll
        for (int ctc = 0; ctc < 4; ++ctc) {
            const int c0 = ctc * 64;
            #pragma unroll
            for (int i = 0; i < 4; ++i) {
                f4v v = *(const f4v*)(x + ((size_t)(b * 256 + c0 + cl + i * 16)) * MTOT + m0 + ml);
                uintT* w = (uintT*)&tile1[(cl + i * 16) * 66 + ml];
                w[0] = pack2(v.x, v.y);
                w[1] = pack2(v.z, v.w);
            }
            __syncthreads();
            s8v o0, o1;
            #pragma unroll
            for (int u = 0; u < 8; ++u) o0[u] = (short)tile1[(cc + u) * 66 + mr];
            #pragma unroll
            for (int u = 0; u < 8; ++u) o1[u] = (short)tile1[(cc + 8 + u) * 66 + mr];
            *(s8v*)&xtile[mr * XT_STRIDE + c0 + cc]     = o0;
            *(s8v*)&xtile[mr * XT_STRIDE + c0 + cc + 8] = o1;
            __syncthreads();                 // tile1 reads done before next chunk
        }
    }

    // ---- stream xtile -> global xt (coalesced, fire-and-forget) ----
    {
        const char* lsrc = (const char*)xtile;
        char* gdst = (char*)(xt + xtb);
        #pragma unroll
        for (int i = 0; i < 8; ++i)
            *(s8v*)(gdst + i * 4096 + t * 16) = *(const s8v*)(lsrc + i * 4096 + t * 16);
        *(uintT*)(gdst + 32768 + t * 4) = *(const uintT*)(lsrc + 32768 + t * 4);
    }

    // ---- MFMA phase (identical math to previous k_qk) ----
    const ushortT* xb = xtile;

    f4v accA[4], sQ[4], sK[4];
    #pragma unroll
    for (int i = 0; i < 4; ++i) {
        accA[i] = (f4v){0,0,0,0};
        sQ[i]   = (f4v){0,0,0,0};
        sK[i]   = (f4v){0,0,0,0};
    }
    s8v ones;
    #pragma unroll
    for (int u = 0; u < 8; ++u) ones[u] = (short)0x3F80;   // bf16 1.0

    const ushortT* wq_base = wqk + (wv * 64 + l15) * 256 + quad * 8;

    #pragma unroll
    for (int op = 0; op < 2; ++op) {              // ot-pair split: caps live regs
        f4v aq[2][4], ak[2][4];
        #pragma unroll
        for (int oo = 0; oo < 2; ++oo)
            #pragma unroll
            for (int j = 0; j < 4; ++j) { aq[oo][j] = (f4v){0,0,0,0}; ak[oo][j] = (f4v){0,0,0,0}; }

        #pragma unroll 2
        for (int kc = 0; kc < 8; ++kc) {
            s8v afq[2], afk[2], bfv[4];
            #pragma unroll
            for (int oo = 0; oo < 2; ++oo) {
                const ushortT* wb = wq_base + (op * 2 + oo) * 16 * 256 + kc * 32;
                afq[oo] = *(const s8v*)wb;
                afk[oo] = *(const s8v*)(wb + 65536);
            }
            #pragma unroll
            for (int j = 0; j < 4; ++j)
                bfv[j] = *(const s8v*)&xb[(j * 16 + l15) * XT_STRIDE + kc * 32 + quad * 8];
            #pragma unroll
            for (int oo = 0; oo < 2; ++oo)
                #pragma unroll
                for (int j = 0; j < 4; ++j)
                    aq[oo][j] = MFMA16(afq[oo], bfv[j], aq[oo][j]);
            #pragma unroll
            for (int oo = 0; oo < 2; ++oo)
                #pragma unroll
                for (int j = 0; j < 4; ++j)
                    ak[oo][j] = MFMA16(afk[oo], bfv[j], ak[oo][j]);
        }

        // elu in place (C layout: row = (op*2+oo)*16+quad*4+r, m = j*16+l15)
        #pragma unroll
        for (int oo = 0; oo < 2; ++oo)
            #pragma unroll
            for (int j = 0; j < 4; ++j)
                #pragma unroll
                for (int r = 0; r < 4; ++r) {
                    aq[oo][j][r] = elu1(aq[oo][j][r]);
                    ak[oo][j][r] = elu1(ak[oo][j][r]);
                }

        // Gram + row sums: q rows 0..15, k rows 16..31 of per-wave region.
        #pragma unroll
        for (int oo = 0; oo < 2; ++oo) {
            const int ot = op * 2 + oo;
            #pragma unroll
            for (int hf = 0; hf < 2; ++hf) {
                #pragma unroll
                for (int jj = 0; jj < 2; ++jj)
                    #pragma unroll
                    for (int r = 0; r < 4; ++r) {
                        int d = quad * 4 + r;
                        gram[d * 40 + jj * 16 + l15]        = f2bf(aq[oo][hf * 2 + jj][r]);
                        gram[(16 + d) * 40 + jj * 16 + l15] = f2bf(ak[oo][hf * 2 + jj][r]);
                    }
                s8v qa = *(const s8v*)&gram[l15 * 40 + quad * 8];
                s8v kb = *(const s8v*)&gram[(16 + l15) * 40 + quad * 8];
                accA[ot] = MFMA16(qa, kb, accA[ot]);
                sQ[ot]   = MFMA16(qa, ones, sQ[ot]);
                sK[ot]   = MFMA16(kb, ones, sK[ot]);
            }
        }
    }

    // final: Ag atomics (full 64B lines)
    #pragma unroll
    for (int ot = 0; ot < 4; ++ot)
        #pragma unroll
        for (int r = 0; r < 4; ++r)
            atomicAdd(Ag + ((b * 16 + wv * 4 + ot) * 16 + quad * 4 + r) * 16 + l15, accA[ot][r]);

    // final: qsum/ksum via gram region -> one coalesced 64-lane atomic each.
    if (l15 == 0) {
        #pragma unroll
        for (int ot = 0; ot < 4; ++ot)
            #pragma unroll
            for (int r = 0; r < 4; ++r) {
                int row = ot * 16 + quad * 4 + r;
                gramf[row]      = sQ[ot][r];
                gramf[64 + row] = sK[ot][r];
            }
    }
    float myq = gramf[lane];
    float myk = gramf[64 + lane];
    atomicAdd(qsg + b * 256 + wv * 64 + lane, myq);
    atomicAdd(ksg + b * 256 + wv * 64 + lane, myk);
}

// K2: Weff[b, h*16+d, c] = z[b,d] * sum_e A[b,h,d,e] * wv[h*16+e, c]  (z of HEAD d)
__global__ __launch_bounds__(256) void k_weff(
    const float* __restrict__ wvw, const float* __restrict__ Ag,
    const float* __restrict__ qsg, const float* __restrict__ ksg,
    ushortT* __restrict__ weff)
{
    __shared__ float A_l[256];
    __shared__ float z_l[16];
    const int t = threadIdx.x;
    const int h = blockIdx.x, b = blockIdx.y;
    A_l[t] = Ag[(b * 16 + h) * 256 + t];
    if (t < 16) {
        float s = 0.f;
        #pragma unroll
        for (int d = 0; d < 16; ++d)
            s += qsg[b * 256 + t * 16 + d] * ksg[b * 256 + t * 16 + d];
        z_l[t] = 1.f / (s + 1e-6f);
    }
    __syncthreads();
    float acc[16];
    #pragma unroll
    for (int d = 0; d < 16; ++d) acc[d] = 0.f;
    #pragma unroll 4
    for (int e = 0; e < 16; ++e) {
        float w = wvw[(h * 16 + e) * 256 + t];
        #pragma unroll
        for (int d = 0; d < 16; ++d) acc[d] += A_l[d * 16 + e] * w;
    }
    #pragma unroll
    for (int d = 0; d < 16; ++d)
        weff[((size_t)b * 256 + h * 16 + d) * 256 + t] = f2bf(acc[d] * z_l[d]);
}

// K3: out[b] = Weff[b] @ x[b]. grid (256, 8): ONE 64-row m-tile per block.
// LDS 33792 B -> 4 blocks/CU; acc[4][4]+frags fit 128 VGPR.
__global__ __launch_bounds__(256, 4) void k_out(
    const ushortT* __restrict__ xt, const ushortT* __restrict__ weff,
    float* __restrict__ out)
{
    __shared__ __align__(16) ushortT lds[XB64_SH];   // 33792 B
    const int t = threadIdx.x;
    const int wv = t >> 6, lane = t & 63, quad = lane >> 4, l15 = lane & 15;
    const int b = blockIdx.y;
    const size_t xtb = (size_t)b * XT_BATCH + (size_t)(blockIdx.x * 64) * XT_STRIDE;

    const ushortT* w_base = weff + (size_t)b * 65536 + (wv * 64 + l15) * 256 + quad * 8;

    STAGE64();
    __syncthreads();
    const ushortT* xb = lds;

    f4v acc[4][4];
    #pragma unroll
    for (int i = 0; i < 4; ++i)
        #pragma unroll
        for (int j = 0; j < 4; ++j) acc[i][j] = (f4v){0,0,0,0};

    #pragma unroll 2
    for (int kc = 0; kc < 8; ++kc) {
        s8v af[4], bfv[4];
        #pragma unroll
        for (int ot = 0; ot < 4; ++ot)
            af[ot] = *(const s8v*)(w_base + ot * 16 * 256 + kc * 32);
        #pragma unroll
        for (int j = 0; j < 4; ++j)
            bfv[j] = *(const s8v*)&xb[(j * 16 + l15) * XT_STRIDE + kc * 32 + quad * 8];
        #pragma unroll
        for (int ot = 0; ot < 4; ++ot)
            #pragma unroll
            for (int j = 0; j < 4; ++j)
                acc[ot][j] = MFMA16(af[ot], bfv[j], acc[ot][j]);
    }

    const int m0 = blockIdx.x * 64;
    #pragma unroll
    for (int ot = 0; ot < 4; ++ot)
        #pragma unroll
        for (int j = 0; j < 4; ++j)
            #pragma unroll
            for (int r = 0; r < 4; ++r)
                out[((size_t)b * 256 + wv * 64 + ot * 16 + quad * 4 + r) * MTOT
                    + m0 + j * 16 + l15] = acc[ot][j][r];
}

extern "C" void kernel_launch(void* const* d_in, const int* in_sizes, int n_in,
                              void* d_out, int out_size, void* d_ws, size_t ws_size,
                              hipStream_t stream)
{
    const float* x   = (const float*)d_in[0];
    const float* wq  = (const float*)d_in[1];
    const float* wk  = (const float*)d_in[2];
    const float* wvw = (const float*)d_in[3];
    float* out = (float*)d_out;
    char* ws = (char*)d_ws;
    // ws layout: wqk bf16 262144 | Ag 131072 | qsg 8192 | ksg 8192 | weff 1048576 | xt 69206016
    ushortT* wqk  = (ushortT*)ws;
    float*   Ag   = (float*)(ws + 262144);
    float*   qsg  = (float*)(ws + 393216);
    float*   ksg  = (float*)(ws + 401408);
    ushortT* weff = (ushortT*)(ws + 409600);
    ushortT* xt   = (ushortT*)(ws + 1458176);

    hipLaunchKernelGGL(k_prep, dim3(256), dim3(256), 0, stream, wq, wk, wqk, Ag);
    hipLaunchKernelGGL(k_qkt,  dim3(256, 8), dim3(256), 0, stream, x, wqk, xt, Ag, qsg, ksg);
    hipLaunchKernelGGL(k_weff, dim3(16, 8),  dim3(256), 0, stream, wvw, Ag, qsg, ksg, weff);
    hipLaunchKernelGGL(k_out,  dim3(256, 8), dim3(256), 0, stream, xt, weff, out);
}